// Round 1
// baseline (1075.485 us; speedup 1.0000x reference)
//
#include <hip/hip_runtime.h>

// ---------------------------------------------------------------------------
// 2-layer GCN: out = A_norm @ relu(A_norm @ (x@W1) + b1) @ W2 ... (+b2)
// A_norm = D^-1/2 (A + I) D^-1/2, factored as out[d] = dinv[d]*sum(g[src]) + b
// with g = dinv * (x @ W). CSR (sorted-by-dst) built once per launch via
// counting sort; reused by both layers.
// ---------------------------------------------------------------------------

__global__ void k_init_counts(int* __restrict__ counts, int n) {
    int i = blockIdx.x * blockDim.x + threadIdx.x;
    if (i < n) counts[i] = 1;  // self-loop
}

__global__ void k_hist(const int* __restrict__ dst, int* __restrict__ counts, int e) {
    int stride = gridDim.x * blockDim.x;
    for (int i = blockIdx.x * blockDim.x + threadIdx.x; i < e; i += stride)
        atomicAdd(&counts[dst[i]], 1);
}

__global__ void k_dinv(const int* __restrict__ counts, float* __restrict__ dinv, int n) {
    int i = blockIdx.x * blockDim.x + threadIdx.x;
    if (i < n) dinv[i] = rsqrtf((float)counts[i]);  // deg >= 1 always (self-loop)
}

// Exclusive scan of counts -> row_ptr.  1024 items per block.
__global__ void k_scan1(const int* __restrict__ counts, int* __restrict__ row_ptr,
                        int* __restrict__ partials, int n) {
    __shared__ int sd[256];
    int t = threadIdx.x;
    int base = blockIdx.x * 1024 + t * 4;
    int c[4];
#pragma unroll
    for (int j = 0; j < 4; j++) c[j] = (base + j < n) ? counts[base + j] : 0;
    int s = c[0] + c[1] + c[2] + c[3];
    sd[t] = s;
    __syncthreads();
    for (int off = 1; off < 256; off <<= 1) {
        int v = (t >= off) ? sd[t - off] : 0;
        __syncthreads();
        sd[t] += v;
        __syncthreads();
    }
    int excl = sd[t] - s;
    if (t == 255) partials[blockIdx.x] = sd[255];
    int pre = excl;
#pragma unroll
    for (int j = 0; j < 4; j++) {
        if (base + j < n) row_ptr[base + j] = pre;
        pre += c[j];
    }
}

__global__ void k_scan2(int* __restrict__ partials, int nb) {
    __shared__ int sd[128];
    int t = threadIdx.x;
    int v = (t < nb) ? partials[t] : 0;
    sd[t] = v;
    __syncthreads();
    for (int off = 1; off < 128; off <<= 1) {
        int u = (t >= off) ? sd[t - off] : 0;
        __syncthreads();
        sd[t] += u;
        __syncthreads();
    }
    if (t < nb) partials[t] = sd[t] - v;  // exclusive block offsets
}

__global__ void k_scan3(int* __restrict__ row_ptr, int* __restrict__ cursor,
                        const int* __restrict__ partials, int n, int total) {
    int i = blockIdx.x * blockDim.x + threadIdx.x;
    if (i < n) {
        int v = row_ptr[i] + partials[i >> 10];
        row_ptr[i] = v;
        cursor[i] = v;
    }
    if (i == 0) row_ptr[n] = total;
}

// Counting-sort fill: real edges then self-loops.
__global__ void k_fill(const int* __restrict__ src, const int* __restrict__ dst,
                       int* __restrict__ cursor, int* __restrict__ srcs, int e, int n) {
    int stride = gridDim.x * blockDim.x;
    int total = e + n;
    for (int i = blockIdx.x * blockDim.x + threadIdx.x; i < total; i += stride) {
        int s, d;
        if (i < e) { s = src[i]; d = dst[i]; }
        else       { s = i - e;  d = s; }
        int pos = atomicAdd(&cursor[d], 1);
        srcs[pos] = s;
    }
}

// G[r][:] = dinv[r] * (X @ W)[r][:]   (X: Mx128, W: 128x128, f32)
// block: 256 threads, 64 rows x 128 cols per block, thread tile 4x8.
__global__ __launch_bounds__(256) void k_gemm_scale(
    const float* __restrict__ X, const float* __restrict__ W,
    const float* __restrict__ dinv, float* __restrict__ G, int M) {
    __shared__ float As[64][36];   // padded: 36%4==0 keeps float4 writes aligned
    __shared__ float Bs[32][132];
    int tid = threadIdx.x;
    int row0 = blockIdx.x * 64;
    int tx = tid & 15, ty = tid >> 4;
    float acc[4][8];
#pragma unroll
    for (int i = 0; i < 4; i++)
#pragma unroll
        for (int j = 0; j < 8; j++) acc[i][j] = 0.f;

    int lr = tid >> 2, lk = (tid & 3) * 8;   // A loader: 64 rows x 32 k
    int bk = tid >> 3, bc = (tid & 7) * 16;  // B loader: 32 k x 128 cols

    for (int k0 = 0; k0 < 128; k0 += 32) {
        int rr = row0 + lr;
        if (rr >= M) rr = M - 1;
        const float* ap = X + (size_t)rr * 128 + k0 + lk;
        float4 a0 = ((const float4*)ap)[0];
        float4 a1 = ((const float4*)ap)[1];
        const float* bp = W + (size_t)(k0 + bk) * 128 + bc;
        float4 w0 = ((const float4*)bp)[0];
        float4 w1 = ((const float4*)bp)[1];
        float4 w2 = ((const float4*)bp)[2];
        float4 w3 = ((const float4*)bp)[3];
        __syncthreads();
        *(float4*)&As[lr][lk] = a0;
        *(float4*)&As[lr][lk + 4] = a1;
        *(float4*)&Bs[bk][bc] = w0;
        *(float4*)&Bs[bk][bc + 4] = w1;
        *(float4*)&Bs[bk][bc + 8] = w2;
        *(float4*)&Bs[bk][bc + 12] = w3;
        __syncthreads();
#pragma unroll
        for (int kk = 0; kk < 32; kk++) {
            float a[4];
#pragma unroll
            for (int i = 0; i < 4; i++) a[i] = As[ty * 4 + i][kk];
            float4 b0 = *(const float4*)&Bs[kk][tx * 8];
            float4 b1 = *(const float4*)&Bs[kk][tx * 8 + 4];
#pragma unroll
            for (int i = 0; i < 4; i++) {
                acc[i][0] += a[i] * b0.x; acc[i][1] += a[i] * b0.y;
                acc[i][2] += a[i] * b0.z; acc[i][3] += a[i] * b0.w;
                acc[i][4] += a[i] * b1.x; acc[i][5] += a[i] * b1.y;
                acc[i][6] += a[i] * b1.z; acc[i][7] += a[i] * b1.w;
            }
        }
    }
#pragma unroll
    for (int i = 0; i < 4; i++) {
        int rg = row0 + ty * 4 + i;
        if (rg < M) {
            float dv = dinv[rg];
            float4 o0 = make_float4(acc[i][0] * dv, acc[i][1] * dv,
                                    acc[i][2] * dv, acc[i][3] * dv);
            float4 o1 = make_float4(acc[i][4] * dv, acc[i][5] * dv,
                                    acc[i][6] * dv, acc[i][7] * dv);
            *(float4*)(G + (size_t)rg * 128 + tx * 8) = o0;
            *(float4*)(G + (size_t)rg * 128 + tx * 8 + 4) = o1;
        }
    }
}

// One wave per dst node; 2 channels per lane; CSR gather + accumulate.
template <int RELU>
__global__ __launch_bounds__(256) void k_aggregate(
    const int* __restrict__ row_ptr, const int* __restrict__ srcs,
    const float* __restrict__ G, const float* __restrict__ dinv,
    const float* __restrict__ bias, float* __restrict__ Out, int n) {
    int wid = (blockIdx.x * 256 + threadIdx.x) >> 6;
    int lane = threadIdx.x & 63;
    if (wid >= n) return;
    int beg = row_ptr[wid], end = row_ptr[wid + 1];
    int c = lane * 2;
    float a0 = 0.f, a1 = 0.f;
    int p = beg;
    for (; p + 4 <= end; p += 4) {
        int s0 = srcs[p], s1 = srcs[p + 1], s2 = srcs[p + 2], s3 = srcs[p + 3];
        float2 v0 = *(const float2*)(G + (size_t)s0 * 128 + c);
        float2 v1 = *(const float2*)(G + (size_t)s1 * 128 + c);
        float2 v2 = *(const float2*)(G + (size_t)s2 * 128 + c);
        float2 v3 = *(const float2*)(G + (size_t)s3 * 128 + c);
        a0 += v0.x + v1.x + v2.x + v3.x;
        a1 += v0.y + v1.y + v2.y + v3.y;
    }
    for (; p < end; p++) {
        int s = srcs[p];
        float2 v = *(const float2*)(G + (size_t)s * 128 + c);
        a0 += v.x; a1 += v.y;
    }
    float dv = dinv[wid];
    a0 = fmaf(a0, dv, bias[c]);
    a1 = fmaf(a1, dv, bias[c + 1]);
    if (RELU) { a0 = fmaxf(a0, 0.f); a1 = fmaxf(a1, 0.f); }
    *(float2*)(Out + (size_t)wid * 128 + c) = make_float2(a0, a1);
}

extern "C" void kernel_launch(void* const* d_in, const int* in_sizes, int n_in,
                              void* d_out, int out_size, void* d_ws, size_t ws_size,
                              hipStream_t stream) {
    const float* x  = (const float*)d_in[0];
    const int*   ei = (const int*)d_in[1];
    const float* W1 = (const float*)d_in[2];
    const float* b1 = (const float*)d_in[3];
    const float* W2 = (const float*)d_in[4];
    const float* b2 = (const float*)d_in[5];
    float* out = (float*)d_out;

    const int C = 128;
    const int N = in_sizes[0] / C;
    const int E = in_sizes[1] / 2;
    const int* src = ei;
    const int* dst = ei + E;
    const int total = E + N;

    char* ws = (char*)d_ws;
    size_t off = 0;
    auto alloc = [&](size_t bytes) -> void* {
        void* p = ws + off;
        off = (off + bytes + 511) & ~(size_t)511;
        return p;
    };
    int*   counts   = (int*)alloc((size_t)N * 4);
    int*   row_ptr  = (int*)alloc(((size_t)N + 1) * 4);
    int*   cursor   = (int*)alloc((size_t)N * 4);
    int*   partials = (int*)alloc(4096);
    float* dinv     = (float*)alloc((size_t)N * 4);
    int*   srcs     = (int*)alloc((size_t)total * 4);
    float* gbuf     = (float*)alloc((size_t)N * C * 4);

    int nblk = (N + 255) / 256;
    int nb = (N + 1023) / 1024;  // scan blocks (98 for N=100k, <=128 supported)

    // ---- graph preprocessing (shared by both layers) ----
    k_init_counts<<<nblk, 256, 0, stream>>>(counts, N);
    k_hist<<<1024, 256, 0, stream>>>(dst, counts, E);
    k_dinv<<<nblk, 256, 0, stream>>>(counts, dinv, N);
    k_scan1<<<nb, 256, 0, stream>>>(counts, row_ptr, partials, N);
    k_scan2<<<1, 128, 0, stream>>>(partials, nb);
    k_scan3<<<nblk, 256, 0, stream>>>(row_ptr, cursor, partials, N, total);
    k_fill<<<2048, 256, 0, stream>>>(src, dst, cursor, srcs, E, N);

    // ---- layer 1: g = dinv*(x@W1); out(d_out) = relu(dinv*sum(g)+b1) ----
    k_gemm_scale<<<(N + 63) / 64, 256, 0, stream>>>(x, W1, dinv, gbuf, N);
    k_aggregate<1><<<(N + 3) / 4, 256, 0, stream>>>(row_ptr, srcs, gbuf, dinv, b1, out, N);

    // ---- layer 2: g = dinv*(relu_out@W2); out = dinv*sum(g)+b2 ----
    k_gemm_scale<<<(N + 63) / 64, 256, 0, stream>>>(out, W2, dinv, gbuf, N);
    k_aggregate<0><<<(N + 3) / 4, 256, 0, stream>>>(row_ptr, srcs, gbuf, dinv, b2, out, N);
}

// Round 2
// 764.347 us; speedup vs baseline: 1.4071x; 1.4071x over previous
//
#include <hip/hip_runtime.h>

// ---------------------------------------------------------------------------
// 2-layer GCN: out = A_norm @ relu(A_norm @ (x@W1) + b1) @ W2 (+b2)
// A_norm = D^-1/2 (A+I) D^-1/2, factored: out[d] = dinv[d]*sum_src(g[src]) + b
// with g = dinv * (x @ W).
//
// CSR build (R1 redesign): two-level counting sort to kill scatter-write
// amplification (R0: k_fill wrote 198 MB HBM for a 13 MB array).
//   pass 0: bucket histogram (dst>>7), LDS-privatized
//   pass 1: partition (s,d) pairs into bucket regions; per-tile LDS histogram
//           + one global reservation per bucket -> contiguous write runs
//   pass 2: one WG per bucket: per-node counts/scan/row_ptr/dinv/fine-sort,
//           all atomics in LDS; srcs writes confined to the WG's ~17 KB region
// ---------------------------------------------------------------------------

#define NPB 128          // nodes per bucket (dst >> 7)
#define NBMAX 1024       // supports N <= 131072
#define EPT 64           // edges per thread in partition kernel
#define PART_TILE (256 * EPT)

__global__ void k_zero(int* __restrict__ p, int n) {
    int i = blockIdx.x * blockDim.x + threadIdx.x;
    if (i < n) p[i] = 0;
}

// Pass 0: histogram of dst>>7 (incl. self-loops: virtual edges E..E+N-1).
__global__ __launch_bounds__(256) void k_bucket_hist(
    const int* __restrict__ dst, int* __restrict__ bucket_count,
    int e, int n, int total) {
    __shared__ int hist[NBMAX];
    int nb = (n + NPB - 1) >> 7;
    int t = threadIdx.x;
    for (int k = t; k < nb; k += 256) hist[k] = 0;
    __syncthreads();
    int stride = gridDim.x * 256;
    for (int i = blockIdx.x * 256 + t; i < total; i += stride) {
        int d = (i < e) ? dst[i] : (i - e);
        atomicAdd(&hist[d >> 7], 1);
    }
    __syncthreads();
    for (int k = t; k < nb; k += 256) {
        int c = hist[k];
        if (c) atomicAdd(&bucket_count[k], c);
    }
}

// Exclusive scan of bucket_count -> bucket_ptr and bucket_cursor. 1 WG.
__global__ __launch_bounds__(256) void k_bucket_scan(
    const int* __restrict__ bucket_count, int* __restrict__ bucket_ptr,
    int* __restrict__ bucket_cursor, int nb, int total) {
    __shared__ int sd[256];
    int t = threadIdx.x;
    int c[4];
#pragma unroll
    for (int j = 0; j < 4; j++) {
        int k = t * 4 + j;
        c[j] = (k < nb) ? bucket_count[k] : 0;
    }
    int s = c[0] + c[1] + c[2] + c[3];
    sd[t] = s;
    __syncthreads();
    for (int off = 1; off < 256; off <<= 1) {
        int v = (t >= off) ? sd[t - off] : 0;
        __syncthreads();
        sd[t] += v;
        __syncthreads();
    }
    int pre = sd[t] - s;
#pragma unroll
    for (int j = 0; j < 4; j++) {
        int k = t * 4 + j;
        if (k < nb) { bucket_ptr[k] = pre; bucket_cursor[k] = pre; }
        pre += c[j];
    }
    if (t == 255) bucket_ptr[nb] = total;
}

// Pass 1: partition (src,dst) pairs into bucket regions.
// Per tile: LDS histogram -> one global atomic per bucket to reserve a run ->
// positioned writes (contiguous ~run-length PART_TILE/nb per bucket).
__global__ __launch_bounds__(256) void k_partition(
    const int* __restrict__ src, const int* __restrict__ dst,
    int* __restrict__ bucket_cursor, int2* __restrict__ pairs,
    int e, int n, int total) {
    __shared__ int hist[NBMAX];
    __shared__ int base[NBMAX];
    int nb = (n + NPB - 1) >> 7;
    int t = threadIdx.x;
    int t0 = blockIdx.x * PART_TILE;
    for (int k = t; k < nb; k += 256) hist[k] = 0;
    __syncthreads();
#pragma unroll 4
    for (int j = 0; j < EPT; j++) {
        int i = t0 + j * 256 + t;
        if (i < total) {
            int d = (i < e) ? dst[i] : (i - e);
            atomicAdd(&hist[d >> 7], 1);
        }
    }
    __syncthreads();
    for (int k = t; k < nb; k += 256) {
        int c = hist[k];
        base[k] = c ? atomicAdd(&bucket_cursor[k], c) : 0;
        hist[k] = 0;  // reuse as local cursor
    }
    __syncthreads();
#pragma unroll 4
    for (int j = 0; j < EPT; j++) {
        int i = t0 + j * 256 + t;
        if (i < total) {
            int s, d;
            if (i < e) { s = src[i]; d = dst[i]; }
            else       { s = i - e;  d = s; }
            int b = d >> 7;
            int off = atomicAdd(&hist[b], 1);
            pairs[base[b] + off] = make_int2(s, d);
        }
    }
}

// Pass 2: one WG per bucket. LDS-only per-node counts, scan, row_ptr, dinv,
// fine counting-sort of srcs into [bucket_ptr[b], bucket_ptr[b+1]).
__global__ __launch_bounds__(256) void k_build(
    const int2* __restrict__ pairs, const int* __restrict__ bucket_ptr,
    int* __restrict__ row_ptr, int* __restrict__ srcs,
    float* __restrict__ dinv, int n) {
    __shared__ int cnt[NPB];
    __shared__ int scn[NPB];
    __shared__ int cur[NPB];
    int b = blockIdx.x;
    int t = threadIdx.x;
    int node0 = b << 7;
    int p0 = bucket_ptr[b], p1 = bucket_ptr[b + 1];
    if (t < NPB) cnt[t] = 0;
    __syncthreads();
    for (int i = p0 + t; i < p1; i += 256) {
        int d = pairs[i].y;
        atomicAdd(&cnt[d - node0], 1);
    }
    __syncthreads();
    if (t < NPB) scn[t] = cnt[t];
    __syncthreads();
    for (int off = 1; off < NPB; off <<= 1) {
        int v = (t < NPB && t >= off) ? scn[t - off] : 0;
        __syncthreads();
        if (t < NPB) scn[t] += v;
        __syncthreads();
    }
    if (t < NPB) {
        int incl = scn[t];
        int excl = incl - cnt[t];
        int start = p0 + excl;
        cur[t] = start;
        int node = node0 + t;
        if (node < n) {
            row_ptr[node] = start;
            dinv[node] = rsqrtf((float)cnt[t]);  // deg >= 1 (self-loop)
            if (node == n - 1) row_ptr[n] = p0 + incl;
        }
    }
    __syncthreads();
    for (int i = p0 + t; i < p1; i += 256) {
        int2 pr = pairs[i];
        int pos = atomicAdd(&cur[pr.y - node0], 1);
        srcs[pos] = pr.x;
    }
}

// G[r][:] = dinv[r] * (X @ W)[r][:]   (X: Mx128, W: 128x128, f32)
// block: 256 threads, 64 rows x 128 cols per block, thread tile 4x8.
__global__ __launch_bounds__(256) void k_gemm_scale(
    const float* __restrict__ X, const float* __restrict__ W,
    const float* __restrict__ dinv, float* __restrict__ G, int M) {
    __shared__ float As[64][36];
    __shared__ float Bs[32][132];
    int tid = threadIdx.x;
    int row0 = blockIdx.x * 64;
    int tx = tid & 15, ty = tid >> 4;
    float acc[4][8];
#pragma unroll
    for (int i = 0; i < 4; i++)
#pragma unroll
        for (int j = 0; j < 8; j++) acc[i][j] = 0.f;

    int lr = tid >> 2, lk = (tid & 3) * 8;
    int bk = tid >> 3, bc = (tid & 7) * 16;

    for (int k0 = 0; k0 < 128; k0 += 32) {
        int rr = row0 + lr;
        if (rr >= M) rr = M - 1;
        const float* ap = X + (size_t)rr * 128 + k0 + lk;
        float4 a0 = ((const float4*)ap)[0];
        float4 a1 = ((const float4*)ap)[1];
        const float* bp = W + (size_t)(k0 + bk) * 128 + bc;
        float4 w0 = ((const float4*)bp)[0];
        float4 w1 = ((const float4*)bp)[1];
        float4 w2 = ((const float4*)bp)[2];
        float4 w3 = ((const float4*)bp)[3];
        __syncthreads();
        *(float4*)&As[lr][lk] = a0;
        *(float4*)&As[lr][lk + 4] = a1;
        *(float4*)&Bs[bk][bc] = w0;
        *(float4*)&Bs[bk][bc + 4] = w1;
        *(float4*)&Bs[bk][bc + 8] = w2;
        *(float4*)&Bs[bk][bc + 12] = w3;
        __syncthreads();
#pragma unroll
        for (int kk = 0; kk < 32; kk++) {
            float a[4];
#pragma unroll
            for (int i = 0; i < 4; i++) a[i] = As[ty * 4 + i][kk];
            float4 b0 = *(const float4*)&Bs[kk][tx * 8];
            float4 b1 = *(const float4*)&Bs[kk][tx * 8 + 4];
#pragma unroll
            for (int i = 0; i < 4; i++) {
                acc[i][0] += a[i] * b0.x; acc[i][1] += a[i] * b0.y;
                acc[i][2] += a[i] * b0.z; acc[i][3] += a[i] * b0.w;
                acc[i][4] += a[i] * b1.x; acc[i][5] += a[i] * b1.y;
                acc[i][6] += a[i] * b1.z; acc[i][7] += a[i] * b1.w;
            }
        }
    }
#pragma unroll
    for (int i = 0; i < 4; i++) {
        int rg = row0 + ty * 4 + i;
        if (rg < M) {
            float dv = dinv[rg];
            float4 o0 = make_float4(acc[i][0] * dv, acc[i][1] * dv,
                                    acc[i][2] * dv, acc[i][3] * dv);
            float4 o1 = make_float4(acc[i][4] * dv, acc[i][5] * dv,
                                    acc[i][6] * dv, acc[i][7] * dv);
            *(float4*)(G + (size_t)rg * 128 + tx * 8) = o0;
            *(float4*)(G + (size_t)rg * 128 + tx * 8 + 4) = o1;
        }
    }
}

// One wave per dst node; 2 channels per lane; CSR gather + accumulate.
template <int RELU>
__global__ __launch_bounds__(256) void k_aggregate(
    const int* __restrict__ row_ptr, const int* __restrict__ srcs,
    const float* __restrict__ G, const float* __restrict__ dinv,
    const float* __restrict__ bias, float* __restrict__ Out, int n) {
    int wid = (blockIdx.x * 256 + threadIdx.x) >> 6;
    int lane = threadIdx.x & 63;
    if (wid >= n) return;
    int beg = row_ptr[wid], end = row_ptr[wid + 1];
    int c = lane * 2;
    float a0 = 0.f, a1 = 0.f;
    int p = beg;
    for (; p + 4 <= end; p += 4) {
        int s0 = srcs[p], s1 = srcs[p + 1], s2 = srcs[p + 2], s3 = srcs[p + 3];
        float2 v0 = *(const float2*)(G + (size_t)s0 * 128 + c);
        float2 v1 = *(const float2*)(G + (size_t)s1 * 128 + c);
        float2 v2 = *(const float2*)(G + (size_t)s2 * 128 + c);
        float2 v3 = *(const float2*)(G + (size_t)s3 * 128 + c);
        a0 += v0.x + v1.x + v2.x + v3.x;
        a1 += v0.y + v1.y + v2.y + v3.y;
    }
    for (; p < end; p++) {
        int s = srcs[p];
        float2 v = *(const float2*)(G + (size_t)s * 128 + c);
        a0 += v.x; a1 += v.y;
    }
    float dv = dinv[wid];
    a0 = fmaf(a0, dv, bias[c]);
    a1 = fmaf(a1, dv, bias[c + 1]);
    if (RELU) { a0 = fmaxf(a0, 0.f); a1 = fmaxf(a1, 0.f); }
    *(float2*)(Out + (size_t)wid * 128 + c) = make_float2(a0, a1);
}

extern "C" void kernel_launch(void* const* d_in, const int* in_sizes, int n_in,
                              void* d_out, int out_size, void* d_ws, size_t ws_size,
                              hipStream_t stream) {
    const float* x  = (const float*)d_in[0];
    const int*   ei = (const int*)d_in[1];
    const float* W1 = (const float*)d_in[2];
    const float* b1 = (const float*)d_in[3];
    const float* W2 = (const float*)d_in[4];
    const float* b2 = (const float*)d_in[5];
    float* out = (float*)d_out;

    const int C = 128;
    const int N = in_sizes[0] / C;
    const int E = in_sizes[1] / 2;
    const int* src = ei;
    const int* dst = ei + E;
    const int total = E + N;
    const int nb = (N + NPB - 1) >> 7;  // 782 for N=100k (<= NBMAX)

    char* ws = (char*)d_ws;
    size_t off = 0;
    auto alloc = [&](size_t bytes) -> void* {
        void* p = ws + off;
        off = (off + bytes + 511) & ~(size_t)511;
        return p;
    };
    int*   bucket_count  = (int*)alloc((size_t)(nb + 1) * 4);
    int*   bucket_ptr    = (int*)alloc((size_t)(nb + 1) * 4);
    int*   bucket_cursor = (int*)alloc((size_t)(nb + 1) * 4);
    int*   row_ptr       = (int*)alloc(((size_t)N + 1) * 4);
    float* dinv          = (float*)alloc((size_t)N * 4);
    int*   srcs          = (int*)alloc((size_t)total * 4);
    float* gbuf          = (float*)alloc((size_t)N * C * 4);
    // pairs (26.4 MB) aliases gbuf (51.2 MB): consumed by k_build before GEMM.
    int2*  pairs         = (int2*)gbuf;

    // ---- CSR build (shared by both layers) ----
    k_zero<<<(nb + 255) / 256, 256, 0, stream>>>(bucket_count, nb);
    k_bucket_hist<<<256, 256, 0, stream>>>(dst, bucket_count, E, N, total);
    k_bucket_scan<<<1, 256, 0, stream>>>(bucket_count, bucket_ptr, bucket_cursor, nb, total);
    k_partition<<<(total + PART_TILE - 1) / PART_TILE, 256, 0, stream>>>(
        src, dst, bucket_cursor, pairs, E, N, total);
    k_build<<<nb, 256, 0, stream>>>(pairs, bucket_ptr, row_ptr, srcs, dinv, N);

    // ---- layer 1: g = dinv*(x@W1); out = relu(dinv*sum(g)+b1) ----
    k_gemm_scale<<<(N + 63) / 64, 256, 0, stream>>>(x, W1, dinv, gbuf, N);
    k_aggregate<1><<<(N + 3) / 4, 256, 0, stream>>>(row_ptr, srcs, gbuf, dinv, b1, out, N);

    // ---- layer 2: g = dinv*(out@W2); out = dinv*sum(g)+b2 ----
    k_gemm_scale<<<(N + 63) / 64, 256, 0, stream>>>(out, W2, dinv, gbuf, N);
    k_aggregate<0><<<(N + 3) / 4, 256, 0, stream>>>(row_ptr, srcs, gbuf, dinv, b2, out, N);
}

// Round 3
// 583.465 us; speedup vs baseline: 1.8433x; 1.3100x over previous
//
#include <hip/hip_runtime.h>

// ---------------------------------------------------------------------------
// 2-layer GCN: out = A_norm @ relu(A_norm @ (x@W1) + b1) @ W2 (+b2)
// A_norm = D^-1/2 (A+I) D^-1/2, factored: out[d] = dinv[d]*sum_src(g[src]) + b
// with g = dinv * (x @ W).
//
// R1: two-level counting sort CSR build (killed 198 MB scatter-write amp).
// R2: G stored as bf16 (rows 512B -> 256B) — the aggregate gather is
//     fabric-BW-bound with zero exploitable locality (random srcs, G >> L2),
//     so halving the payload is the only lever. f32 accumulation throughout.
// ---------------------------------------------------------------------------

#define NPB 128          // nodes per bucket (dst >> 7)
#define NBMAX 1024       // supports N <= 131072
#define EPT 64           // edges per thread in partition kernel
#define PART_TILE (256 * EPT)

__global__ void k_zero(int* __restrict__ p, int n) {
    int i = blockIdx.x * blockDim.x + threadIdx.x;
    if (i < n) p[i] = 0;
}

// Pass 0: histogram of dst>>7 (incl. self-loops: virtual edges E..E+N-1).
__global__ __launch_bounds__(256) void k_bucket_hist(
    const int* __restrict__ dst, int* __restrict__ bucket_count,
    int e, int n, int total) {
    __shared__ int hist[NBMAX];
    int nb = (n + NPB - 1) >> 7;
    int t = threadIdx.x;
    for (int k = t; k < nb; k += 256) hist[k] = 0;
    __syncthreads();
    int stride = gridDim.x * 256;
    for (int i = blockIdx.x * 256 + t; i < total; i += stride) {
        int d = (i < e) ? dst[i] : (i - e);
        atomicAdd(&hist[d >> 7], 1);
    }
    __syncthreads();
    for (int k = t; k < nb; k += 256) {
        int c = hist[k];
        if (c) atomicAdd(&bucket_count[k], c);
    }
}

// Exclusive scan of bucket_count -> bucket_ptr and bucket_cursor. 1 WG.
__global__ __launch_bounds__(256) void k_bucket_scan(
    const int* __restrict__ bucket_count, int* __restrict__ bucket_ptr,
    int* __restrict__ bucket_cursor, int nb, int total) {
    __shared__ int sd[256];
    int t = threadIdx.x;
    int c[4];
#pragma unroll
    for (int j = 0; j < 4; j++) {
        int k = t * 4 + j;
        c[j] = (k < nb) ? bucket_count[k] : 0;
    }
    int s = c[0] + c[1] + c[2] + c[3];
    sd[t] = s;
    __syncthreads();
    for (int off = 1; off < 256; off <<= 1) {
        int v = (t >= off) ? sd[t - off] : 0;
        __syncthreads();
        sd[t] += v;
        __syncthreads();
    }
    int pre = sd[t] - s;
#pragma unroll
    for (int j = 0; j < 4; j++) {
        int k = t * 4 + j;
        if (k < nb) { bucket_ptr[k] = pre; bucket_cursor[k] = pre; }
        pre += c[j];
    }
    if (t == 255) bucket_ptr[nb] = total;
}

// Pass 1: partition (src,dst) pairs into bucket regions.
__global__ __launch_bounds__(256) void k_partition(
    const int* __restrict__ src, const int* __restrict__ dst,
    int* __restrict__ bucket_cursor, int2* __restrict__ pairs,
    int e, int n, int total) {
    __shared__ int hist[NBMAX];
    __shared__ int base[NBMAX];
    int nb = (n + NPB - 1) >> 7;
    int t = threadIdx.x;
    int t0 = blockIdx.x * PART_TILE;
    for (int k = t; k < nb; k += 256) hist[k] = 0;
    __syncthreads();
#pragma unroll 4
    for (int j = 0; j < EPT; j++) {
        int i = t0 + j * 256 + t;
        if (i < total) {
            int d = (i < e) ? dst[i] : (i - e);
            atomicAdd(&hist[d >> 7], 1);
        }
    }
    __syncthreads();
    for (int k = t; k < nb; k += 256) {
        int c = hist[k];
        base[k] = c ? atomicAdd(&bucket_cursor[k], c) : 0;
        hist[k] = 0;  // reuse as local cursor
    }
    __syncthreads();
#pragma unroll 4
    for (int j = 0; j < EPT; j++) {
        int i = t0 + j * 256 + t;
        if (i < total) {
            int s, d;
            if (i < e) { s = src[i]; d = dst[i]; }
            else       { s = i - e;  d = s; }
            int b = d >> 7;
            int off = atomicAdd(&hist[b], 1);
            pairs[base[b] + off] = make_int2(s, d);
        }
    }
}

// Pass 2: one WG per bucket; LDS-only counts/scan/row_ptr/dinv/fine-sort.
__global__ __launch_bounds__(256) void k_build(
    const int2* __restrict__ pairs, const int* __restrict__ bucket_ptr,
    int* __restrict__ row_ptr, int* __restrict__ srcs,
    float* __restrict__ dinv, int n) {
    __shared__ int cnt[NPB];
    __shared__ int scn[NPB];
    __shared__ int cur[NPB];
    int b = blockIdx.x;
    int t = threadIdx.x;
    int node0 = b << 7;
    int p0 = bucket_ptr[b], p1 = bucket_ptr[b + 1];
    if (t < NPB) cnt[t] = 0;
    __syncthreads();
    for (int i = p0 + t; i < p1; i += 256) {
        int d = pairs[i].y;
        atomicAdd(&cnt[d - node0], 1);
    }
    __syncthreads();
    if (t < NPB) scn[t] = cnt[t];
    __syncthreads();
    for (int off = 1; off < NPB; off <<= 1) {
        int v = (t < NPB && t >= off) ? scn[t - off] : 0;
        __syncthreads();
        if (t < NPB) scn[t] += v;
        __syncthreads();
    }
    if (t < NPB) {
        int incl = scn[t];
        int excl = incl - cnt[t];
        int start = p0 + excl;
        cur[t] = start;
        int node = node0 + t;
        if (node < n) {
            row_ptr[node] = start;
            dinv[node] = rsqrtf((float)cnt[t]);  // deg >= 1 (self-loop)
            if (node == n - 1) row_ptr[n] = p0 + incl;
        }
    }
    __syncthreads();
    for (int i = p0 + t; i < p1; i += 256) {
        int2 pr = pairs[i];
        int pos = atomicAdd(&cur[pr.y - node0], 1);
        srcs[pos] = pr.x;
    }
}

__device__ __forceinline__ unsigned short f32_to_bf16_rne(float x) {
    unsigned int v = __float_as_uint(x);
    unsigned int r = v + 0x7fffu + ((v >> 16) & 1u);
    return (unsigned short)(r >> 16);
}

// G[r][:] = bf16( dinv[r] * (X @ W)[r][:] )   (X: Mx128 f32, W: 128x128 f32)
// block: 256 threads, 64 rows x 128 cols per block, thread tile 4x8.
__global__ __launch_bounds__(256) void k_gemm_scale(
    const float* __restrict__ X, const float* __restrict__ W,
    const float* __restrict__ dinv, unsigned short* __restrict__ G, int M) {
    __shared__ float As[64][36];
    __shared__ float Bs[32][132];
    int tid = threadIdx.x;
    int row0 = blockIdx.x * 64;
    int tx = tid & 15, ty = tid >> 4;
    float acc[4][8];
#pragma unroll
    for (int i = 0; i < 4; i++)
#pragma unroll
        for (int j = 0; j < 8; j++) acc[i][j] = 0.f;

    int lr = tid >> 2, lk = (tid & 3) * 8;
    int bk = tid >> 3, bc = (tid & 7) * 16;

    for (int k0 = 0; k0 < 128; k0 += 32) {
        int rr = row0 + lr;
        if (rr >= M) rr = M - 1;
        const float* ap = X + (size_t)rr * 128 + k0 + lk;
        float4 a0 = ((const float4*)ap)[0];
        float4 a1 = ((const float4*)ap)[1];
        const float* bp = W + (size_t)(k0 + bk) * 128 + bc;
        float4 w0 = ((const float4*)bp)[0];
        float4 w1 = ((const float4*)bp)[1];
        float4 w2 = ((const float4*)bp)[2];
        float4 w3 = ((const float4*)bp)[3];
        __syncthreads();
        *(float4*)&As[lr][lk] = a0;
        *(float4*)&As[lr][lk + 4] = a1;
        *(float4*)&Bs[bk][bc] = w0;
        *(float4*)&Bs[bk][bc + 4] = w1;
        *(float4*)&Bs[bk][bc + 8] = w2;
        *(float4*)&Bs[bk][bc + 12] = w3;
        __syncthreads();
#pragma unroll
        for (int kk = 0; kk < 32; kk++) {
            float a[4];
#pragma unroll
            for (int i = 0; i < 4; i++) a[i] = As[ty * 4 + i][kk];
            float4 b0 = *(const float4*)&Bs[kk][tx * 8];
            float4 b1 = *(const float4*)&Bs[kk][tx * 8 + 4];
#pragma unroll
            for (int i = 0; i < 4; i++) {
                acc[i][0] += a[i] * b0.x; acc[i][1] += a[i] * b0.y;
                acc[i][2] += a[i] * b0.z; acc[i][3] += a[i] * b0.w;
                acc[i][4] += a[i] * b1.x; acc[i][5] += a[i] * b1.y;
                acc[i][6] += a[i] * b1.z; acc[i][7] += a[i] * b1.w;
            }
        }
    }
#pragma unroll
    for (int i = 0; i < 4; i++) {
        int rg = row0 + ty * 4 + i;
        if (rg < M) {
            float dv = dinv[rg];
            union { unsigned short us[8]; uint4 u4; } pk;
#pragma unroll
            for (int j = 0; j < 8; j++) pk.us[j] = f32_to_bf16_rne(acc[i][j] * dv);
            *(uint4*)(G + (size_t)rg * 128 + tx * 8) = pk.u4;
        }
    }
}

// One wave per dst node; 2 channels per lane (one dword of bf16x2 per row).
template <int RELU>
__global__ __launch_bounds__(256) void k_aggregate(
    const int* __restrict__ row_ptr, const int* __restrict__ srcs,
    const unsigned short* __restrict__ G, const float* __restrict__ dinv,
    const float* __restrict__ bias, float* __restrict__ Out, int n) {
    int wid = (blockIdx.x * 256 + threadIdx.x) >> 6;
    int lane = threadIdx.x & 63;
    if (wid >= n) return;
    int beg = row_ptr[wid], end = row_ptr[wid + 1];
    int c = lane * 2;
    float a0 = 0.f, a1 = 0.f;
    int p = beg;
    for (; p + 4 <= end; p += 4) {
        int s0 = srcs[p], s1 = srcs[p + 1], s2 = srcs[p + 2], s3 = srcs[p + 3];
        unsigned int u0 = *(const unsigned int*)(G + (size_t)s0 * 128 + c);
        unsigned int u1 = *(const unsigned int*)(G + (size_t)s1 * 128 + c);
        unsigned int u2 = *(const unsigned int*)(G + (size_t)s2 * 128 + c);
        unsigned int u3 = *(const unsigned int*)(G + (size_t)s3 * 128 + c);
        a0 += __uint_as_float(u0 << 16) + __uint_as_float(u1 << 16) +
              __uint_as_float(u2 << 16) + __uint_as_float(u3 << 16);
        a1 += __uint_as_float(u0 & 0xffff0000u) + __uint_as_float(u1 & 0xffff0000u) +
              __uint_as_float(u2 & 0xffff0000u) + __uint_as_float(u3 & 0xffff0000u);
    }
    for (; p < end; p++) {
        int s = srcs[p];
        unsigned int u = *(const unsigned int*)(G + (size_t)s * 128 + c);
        a0 += __uint_as_float(u << 16);
        a1 += __uint_as_float(u & 0xffff0000u);
    }
    float dv = dinv[wid];
    a0 = fmaf(a0, dv, bias[c]);
    a1 = fmaf(a1, dv, bias[c + 1]);
    if (RELU) { a0 = fmaxf(a0, 0.f); a1 = fmaxf(a1, 0.f); }
    *(float2*)(Out + (size_t)wid * 128 + c) = make_float2(a0, a1);
}

extern "C" void kernel_launch(void* const* d_in, const int* in_sizes, int n_in,
                              void* d_out, int out_size, void* d_ws, size_t ws_size,
                              hipStream_t stream) {
    const float* x  = (const float*)d_in[0];
    const int*   ei = (const int*)d_in[1];
    const float* W1 = (const float*)d_in[2];
    const float* b1 = (const float*)d_in[3];
    const float* W2 = (const float*)d_in[4];
    const float* b2 = (const float*)d_in[5];
    float* out = (float*)d_out;

    const int C = 128;
    const int N = in_sizes[0] / C;
    const int E = in_sizes[1] / 2;
    const int* src = ei;
    const int* dst = ei + E;
    const int total = E + N;
    const int nb = (N + NPB - 1) >> 7;  // 782 for N=100k (<= NBMAX)

    char* ws = (char*)d_ws;
    size_t off = 0;
    auto alloc = [&](size_t bytes) -> void* {
        void* p = ws + off;
        off = (off + bytes + 511) & ~(size_t)511;
        return p;
    };
    int*   bucket_count  = (int*)alloc((size_t)(nb + 1) * 4);
    int*   bucket_ptr    = (int*)alloc((size_t)(nb + 1) * 4);
    int*   bucket_cursor = (int*)alloc((size_t)(nb + 1) * 4);
    int*   row_ptr       = (int*)alloc(((size_t)N + 1) * 4);
    float* dinv          = (float*)alloc((size_t)N * 4);
    int*   srcs          = (int*)alloc((size_t)total * 4);
    // Shared region: pairs (total*8 B) then later G bf16 (N*C*2 B).
    size_t gbytes = (size_t)N * C * 2;
    size_t pbytes = (size_t)total * 8;
    void*  shared = alloc(gbytes > pbytes ? gbytes : pbytes);
    unsigned short* gbuf = (unsigned short*)shared;
    int2*  pairs         = (int2*)shared;  // consumed by k_build before GEMM

    // ---- CSR build (shared by both layers) ----
    k_zero<<<(nb + 255) / 256, 256, 0, stream>>>(bucket_count, nb);
    k_bucket_hist<<<256, 256, 0, stream>>>(dst, bucket_count, E, N, total);
    k_bucket_scan<<<1, 256, 0, stream>>>(bucket_count, bucket_ptr, bucket_cursor, nb, total);
    k_partition<<<(total + PART_TILE - 1) / PART_TILE, 256, 0, stream>>>(
        src, dst, bucket_cursor, pairs, E, N, total);
    k_build<<<nb, 256, 0, stream>>>(pairs, bucket_ptr, row_ptr, srcs, dinv, N);

    // ---- layer 1: g = bf16(dinv*(x@W1)); out = relu(dinv*sum(g)+b1) ----
    k_gemm_scale<<<(N + 63) / 64, 256, 0, stream>>>(x, W1, dinv, gbuf, N);
    k_aggregate<1><<<(N + 3) / 4, 256, 0, stream>>>(row_ptr, srcs, gbuf, dinv, b1, out, N);

    // ---- layer 2: g = bf16(dinv*(out@W2)); out = dinv*sum(g)+b2 ----
    k_gemm_scale<<<(N + 63) / 64, 256, 0, stream>>>(out, W2, dinv, gbuf, N);
    k_aggregate<0><<<(N + 3) / 4, 256, 0, stream>>>(row_ptr, srcs, gbuf, dinv, b2, out, N);
}

// Round 5
// 547.488 us; speedup vs baseline: 1.9644x; 1.0657x over previous
//
#include <hip/hip_runtime.h>

// ---------------------------------------------------------------------------
// 2-layer GCN: out = A_norm @ relu(A_norm @ (x@W1) + b1) @ W2 (+b2)
// A_norm = D^-1/2 (A+I) D^-1/2, factored: out[d] = dinv[d]*sum_src(g[src]) + b
// with g = dinv * (x @ W).
//
// R1: two-level counting-sort CSR build (killed 198 MB scatter-write amp).
// R2: G stored bf16 (aggregate is L3-fetch-bound; halve the payload).
// R3: MFMA bf16 GEMM (split-A for ~f32 precision), packed 4 B pairs,
//     bf16 layer-1 activation.
// R4: FIX — bf16 A-staging loop loaded 16/32 ushorts per segment, leaving
//     half the LDS tile uninitialized -> NaN via layer-2 MFMA. Now j<4 uint4s.
// Requires N <= 131072 (17-bit src in packed pairs).
// ---------------------------------------------------------------------------

#define NPB 128          // nodes per bucket (dst >> 7)
#define NBMAX 1024       // supports N <= 131072
#define EPT 64           // edges per thread in partition kernel
#define PART_TILE (256 * EPT)

typedef unsigned short ushort_t;
typedef __attribute__((ext_vector_type(8))) short short8;
typedef __attribute__((ext_vector_type(4))) float f32x4;

__device__ __forceinline__ unsigned short f32_to_bf16_rne(float x) {
    unsigned int v = __float_as_uint(x);
    unsigned int r = v + 0x7fffu + ((v >> 16) & 1u);
    return (unsigned short)(r >> 16);
}

__global__ void k_zero(int* __restrict__ p, int n) {
    int i = blockIdx.x * blockDim.x + threadIdx.x;
    if (i < n) p[i] = 0;
}

// W (f32, [k][n]) -> Wprep (bf16, [n][k]) for both layers. 2*16384 elems.
__global__ __launch_bounds__(256) void k_wprep(
    const float* __restrict__ W1, const float* __restrict__ W2,
    ushort_t* __restrict__ Wp1, ushort_t* __restrict__ Wp2) {
    int idx = blockIdx.x * 256 + threadIdx.x;
    int which = idx >> 14;
    int e = idx & 16383;
    int n = e & 127, k = e >> 7;
    const float* W = which ? W2 : W1;
    ushort_t* Wp = which ? Wp2 : Wp1;
    Wp[n * 128 + k] = f32_to_bf16_rne(W[k * 128 + n]);
}

// Pass 0: histogram of dst>>7 (incl. self-loops: virtual edges E..E+N-1).
__global__ __launch_bounds__(256) void k_bucket_hist(
    const int* __restrict__ dst, int* __restrict__ bucket_count,
    int e, int n, int total) {
    __shared__ int hist[NBMAX];
    int nb = (n + NPB - 1) >> 7;
    int t = threadIdx.x;
    for (int k = t; k < nb; k += 256) hist[k] = 0;
    __syncthreads();
    int stride = gridDim.x * 256;
    for (int i = blockIdx.x * 256 + t; i < total; i += stride) {
        int d = (i < e) ? dst[i] : (i - e);
        atomicAdd(&hist[d >> 7], 1);
    }
    __syncthreads();
    for (int k = t; k < nb; k += 256) {
        int c = hist[k];
        if (c) atomicAdd(&bucket_count[k], c);
    }
}

// Exclusive scan of bucket_count -> bucket_ptr and bucket_cursor. 1 WG.
__global__ __launch_bounds__(256) void k_bucket_scan(
    const int* __restrict__ bucket_count, int* __restrict__ bucket_ptr,
    int* __restrict__ bucket_cursor, int nb, int total) {
    __shared__ int sd[256];
    int t = threadIdx.x;
    int c[4];
#pragma unroll
    for (int j = 0; j < 4; j++) {
        int k = t * 4 + j;
        c[j] = (k < nb) ? bucket_count[k] : 0;
    }
    int s = c[0] + c[1] + c[2] + c[3];
    sd[t] = s;
    __syncthreads();
    for (int off = 1; off < 256; off <<= 1) {
        int v = (t >= off) ? sd[t - off] : 0;
        __syncthreads();
        sd[t] += v;
        __syncthreads();
    }
    int pre = sd[t] - s;
#pragma unroll
    for (int j = 0; j < 4; j++) {
        int k = t * 4 + j;
        if (k < nb) { bucket_ptr[k] = pre; bucket_cursor[k] = pre; }
        pre += c[j];
    }
    if (t == 255) bucket_ptr[nb] = total;
}

// Pass 1: partition packed (src | dlow<<17) into bucket regions.
__global__ __launch_bounds__(256) void k_partition(
    const int* __restrict__ src, const int* __restrict__ dst,
    int* __restrict__ bucket_cursor, unsigned int* __restrict__ pairs,
    int e, int n, int total) {
    __shared__ int hist[NBMAX];
    __shared__ int base[NBMAX];
    int nb = (n + NPB - 1) >> 7;
    int t = threadIdx.x;
    int t0 = blockIdx.x * PART_TILE;
    for (int k = t; k < nb; k += 256) hist[k] = 0;
    __syncthreads();
#pragma unroll 4
    for (int j = 0; j < EPT; j++) {
        int i = t0 + j * 256 + t;
        if (i < total) {
            int d = (i < e) ? dst[i] : (i - e);
            atomicAdd(&hist[d >> 7], 1);
        }
    }
    __syncthreads();
    for (int k = t; k < nb; k += 256) {
        int c = hist[k];
        base[k] = c ? atomicAdd(&bucket_cursor[k], c) : 0;
        hist[k] = 0;  // reuse as local cursor
    }
    __syncthreads();
#pragma unroll 4
    for (int j = 0; j < EPT; j++) {
        int i = t0 + j * 256 + t;
        if (i < total) {
            int s, d;
            if (i < e) { s = src[i]; d = dst[i]; }
            else       { s = i - e;  d = s; }
            int b = d >> 7;
            int off = atomicAdd(&hist[b], 1);
            pairs[base[b] + off] = (unsigned int)s | ((unsigned int)(d & 127) << 17);
        }
    }
}

// Pass 2: one WG per bucket; LDS-only counts/scan/row_ptr/dinv/fine-sort.
__global__ __launch_bounds__(256) void k_build(
    const unsigned int* __restrict__ pairs, const int* __restrict__ bucket_ptr,
    int* __restrict__ row_ptr, int* __restrict__ srcs,
    float* __restrict__ dinv, int n) {
    __shared__ int cnt[NPB];
    __shared__ int scn[NPB];
    __shared__ int cur[NPB];
    int b = blockIdx.x;
    int t = threadIdx.x;
    int node0 = b << 7;
    int p0 = bucket_ptr[b], p1 = bucket_ptr[b + 1];
    if (t < NPB) cnt[t] = 0;
    __syncthreads();
    for (int i = p0 + t; i < p1; i += 256) {
        int dlow = (int)(pairs[i] >> 17) & 127;
        atomicAdd(&cnt[dlow], 1);
    }
    __syncthreads();
    if (t < NPB) scn[t] = cnt[t];
    __syncthreads();
    for (int off = 1; off < NPB; off <<= 1) {
        int v = (t < NPB && t >= off) ? scn[t - off] : 0;
        __syncthreads();
        if (t < NPB) scn[t] += v;
        __syncthreads();
    }
    if (t < NPB) {
        int incl = scn[t];
        int excl = incl - cnt[t];
        int start = p0 + excl;
        cur[t] = start;
        int node = node0 + t;
        if (node < n) {
            row_ptr[node] = start;
            dinv[node] = rsqrtf((float)cnt[t]);  // deg >= 1 (self-loop)
            if (node == n - 1) row_ptr[n] = p0 + incl;
        }
    }
    __syncthreads();
    for (int i = p0 + t; i < p1; i += 256) {
        unsigned int pr = pairs[i];
        int pos = atomicAdd(&cur[(pr >> 17) & 127], 1);
        srcs[pos] = (int)(pr & 0x1FFFFu);
    }
}

// ---------------------------------------------------------------------------
// MFMA GEMM: G[r][:] = bf16( dinv[r] * (A @ W)[r][:] ), A: Mx128, W: 128x128.
// Wp is pre-transposed bf16 [n][k]. Block = 256 thr = 4 waves; 64 rows/block,
// wave w owns rows 16w..16w+15 x all 128 cols (8 col-tiles of 16).
// ABF16=false: A is f32; split A = A_hi + A_lo (both bf16) -> 2 MFMA terms.
// ABF16=true:  A already bf16 -> 1 MFMA term.
// mfma_f32_16x16x32_bf16 layouts (HW-verified per guide m89/m91/m120):
//   A: lane holds A[m=lane&15][k=(lane>>4)*8 + j], j=0..7
//   B: lane holds B[k=(lane>>4)*8 + j][n=lane&15]
//   C/D: col=lane&15, row=(lane>>4)*4 + reg
// ---------------------------------------------------------------------------
template <bool ABF16>
__global__ __launch_bounds__(256) void k_gemm_mfma(
    const void* __restrict__ Araw, const ushort_t* __restrict__ Wp,
    const float* __restrict__ dinv, ushort_t* __restrict__ G, int M) {
    // One LDS buffer, template-sized: f32 tile 64x132 (33.8 KB) or bf16 tile
    // 64x136 (17.4 KB). Row strides keep 16 B alignment (528 = 33*16, 272 = 17*16).
    __shared__ char smem[ABF16 ? (64 * 136 * 2) : (64 * 132 * 4)];
    float (*Af32)[132] = (float (*)[132])smem;
    ushort_t (*Au16)[136] = (ushort_t (*)[136])smem;

    int t = threadIdx.x;
    int row0 = blockIdx.x * 64;

    // ---- stage A tile (64 rows x 128 cols); 4 loader threads per row,
    //      each stages a 32-col segment ----
    {
        int r = t >> 2;
        int seg = (t & 3) * 32;
        int gr = row0 + r; if (gr >= M) gr = M - 1;
        if constexpr (!ABF16) {
            const float* ap = (const float*)Araw + (size_t)gr * 128 + seg;
#pragma unroll
            for (int j = 0; j < 8; j++) {   // 8 x float4 = 32 floats
                float4 v = ((const float4*)ap)[j];
                *(float4*)&Af32[r][seg + j * 4] = v;
            }
        } else {
            const ushort_t* ap = (const ushort_t*)Araw + (size_t)gr * 128 + seg;
#pragma unroll
            for (int j = 0; j < 4; j++) {   // 4 x uint4 = 32 ushorts (R4 FIX)
                uint4 v = ((const uint4*)ap)[j];
                *(uint4*)&Au16[r][seg + j * 8] = v;
            }
        }
    }
    __syncthreads();

    int wv = t >> 6;            // wave 0..3 -> rows 16w..16w+15
    int lane = t & 63;
    int m = lane & 15;          // row within wave tile
    int quad = lane >> 4;       // 0..3
    int lrow = wv * 16 + m;     // row within block tile

    f32x4 acc[8];
#pragma unroll
    for (int c = 0; c < 8; c++) acc[c] = (f32x4){0.f, 0.f, 0.f, 0.f};

#pragma unroll
    for (int ks = 0; ks < 4; ks++) {
        int kb = ks * 32 + quad * 8;
        short8 ahi, alo;
        if constexpr (!ABF16) {
            float xs[8];
#pragma unroll
            for (int j = 0; j < 8; j++) xs[j] = Af32[lrow][kb + j];
#pragma unroll
            for (int j = 0; j < 8; j++) {
                unsigned short h = f32_to_bf16_rne(xs[j]);
                ahi[j] = (short)h;
                float hf = __uint_as_float((unsigned int)h << 16);
                alo[j] = (short)f32_to_bf16_rne(xs[j] - hf);
            }
        } else {
            ahi = *(const short8*)&Au16[lrow][kb];
        }
#pragma unroll
        for (int c = 0; c < 8; c++) {
            // B-frag direct from global (Wp is L1/L2-hot, 32 KB)
            short8 b8 = *(const short8*)(Wp + (size_t)(c * 16 + m) * 128 + kb);
            acc[c] = __builtin_amdgcn_mfma_f32_16x16x32_bf16(ahi, b8, acc[c], 0, 0, 0);
            if constexpr (!ABF16)
                acc[c] = __builtin_amdgcn_mfma_f32_16x16x32_bf16(alo, b8, acc[c], 0, 0, 0);
        }
    }

    // ---- epilogue: scale by dinv, pack bf16, store ----
    int rbase = row0 + wv * 16 + quad * 4;
#pragma unroll
    for (int reg = 0; reg < 4; reg++) {
        int gr = rbase + reg;
        if (gr < M) {
            float dv = dinv[gr];
#pragma unroll
            for (int c = 0; c < 8; c++) {
                G[(size_t)gr * 128 + c * 16 + m] = f32_to_bf16_rne(acc[c][reg] * dv);
            }
        }
    }
}

// One wave per dst node; 2 channels per lane (one dword of bf16x2 per row).
template <int RELU, int OUTBF16>
__global__ __launch_bounds__(256) void k_aggregate(
    const int* __restrict__ row_ptr, const int* __restrict__ srcs,
    const ushort_t* __restrict__ G, const float* __restrict__ dinv,
    const float* __restrict__ bias, void* __restrict__ OutRaw, int n) {
    int wid = (blockIdx.x * 256 + threadIdx.x) >> 6;
    int lane = threadIdx.x & 63;
    if (wid >= n) return;
    int beg = row_ptr[wid], end = row_ptr[wid + 1];
    int c = lane * 2;
    float a0 = 0.f, a1 = 0.f;
    int p = beg;
    for (; p + 4 <= end; p += 4) {
        int s0 = srcs[p], s1 = srcs[p + 1], s2 = srcs[p + 2], s3 = srcs[p + 3];
        unsigned int u0 = *(const unsigned int*)(G + (size_t)s0 * 128 + c);
        unsigned int u1 = *(const unsigned int*)(G + (size_t)s1 * 128 + c);
        unsigned int u2 = *(const unsigned int*)(G + (size_t)s2 * 128 + c);
        unsigned int u3 = *(const unsigned int*)(G + (size_t)s3 * 128 + c);
        a0 += __uint_as_float(u0 << 16) + __uint_as_float(u1 << 16) +
              __uint_as_float(u2 << 16) + __uint_as_float(u3 << 16);
        a1 += __uint_as_float(u0 & 0xffff0000u) + __uint_as_float(u1 & 0xffff0000u) +
              __uint_as_float(u2 & 0xffff0000u) + __uint_as_float(u3 & 0xffff0000u);
    }
    for (; p < end; p++) {
        int s = srcs[p];
        unsigned int u = *(const unsigned int*)(G + (size_t)s * 128 + c);
        a0 += __uint_as_float(u << 16);
        a1 += __uint_as_float(u & 0xffff0000u);
    }
    float dv = dinv[wid];
    a0 = fmaf(a0, dv, bias[c]);
    a1 = fmaf(a1, dv, bias[c + 1]);
    if (RELU) { a0 = fmaxf(a0, 0.f); a1 = fmaxf(a1, 0.f); }
    if (OUTBF16) {
        unsigned int u = (unsigned int)f32_to_bf16_rne(a0) |
                         ((unsigned int)f32_to_bf16_rne(a1) << 16);
        ((unsigned int*)OutRaw)[(size_t)wid * 64 + lane] = u;
    } else {
        *(float2*)((float*)OutRaw + (size_t)wid * 128 + c) = make_float2(a0, a1);
    }
}

extern "C" void kernel_launch(void* const* d_in, const int* in_sizes, int n_in,
                              void* d_out, int out_size, void* d_ws, size_t ws_size,
                              hipStream_t stream) {
    const float* x  = (const float*)d_in[0];
    const int*   ei = (const int*)d_in[1];
    const float* W1 = (const float*)d_in[2];
    const float* b1 = (const float*)d_in[3];
    const float* W2 = (const float*)d_in[4];
    const float* b2 = (const float*)d_in[5];
    float* out = (float*)d_out;

    const int C = 128;
    const int N = in_sizes[0] / C;
    const int E = in_sizes[1] / 2;
    const int* src = ei;
    const int* dst = ei + E;
    const int total = E + N;
    const int nb = (N + NPB - 1) >> 7;  // 782 for N=100k (<= NBMAX)

    char* ws = (char*)d_ws;
    size_t off = 0;
    auto alloc = [&](size_t bytes) -> void* {
        void* p = ws + off;
        off = (off + bytes + 511) & ~(size_t)511;
        return p;
    };
    int*   bucket_count  = (int*)alloc((size_t)(nb + 1) * 4);
    int*   bucket_ptr    = (int*)alloc((size_t)(nb + 1) * 4);
    int*   bucket_cursor = (int*)alloc((size_t)(nb + 1) * 4);
    int*   row_ptr       = (int*)alloc(((size_t)N + 1) * 4);
    float* dinv          = (float*)alloc((size_t)N * 4);
    int*   srcs          = (int*)alloc((size_t)total * 4);
    ushort_t* Wp1        = (ushort_t*)alloc(128 * 128 * 2);
    ushort_t* Wp2        = (ushort_t*)alloc(128 * 128 * 2);
    ushort_t* gbuf       = (ushort_t*)alloc((size_t)N * C * 2);   // gathered g
    // act (bf16 layer-1 output, N*C*2) shares with pairs (total*4 B):
    size_t abytes = (size_t)N * C * 2;
    size_t pbytes = (size_t)total * 4;
    void*  shared = alloc(abytes > pbytes ? abytes : pbytes);
    ushort_t* act = (ushort_t*)shared;
    unsigned int* pairs = (unsigned int*)shared;  // dead after k_build

    // ---- weight prep + CSR build (shared by both layers) ----
    k_wprep<<<128, 256, 0, stream>>>(W1, W2, Wp1, Wp2);
    k_zero<<<(nb + 255) / 256, 256, 0, stream>>>(bucket_count, nb);
    k_bucket_hist<<<256, 256, 0, stream>>>(dst, bucket_count, E, N, total);
    k_bucket_scan<<<1, 256, 0, stream>>>(bucket_count, bucket_ptr, bucket_cursor, nb, total);
    k_partition<<<(total + PART_TILE - 1) / PART_TILE, 256, 0, stream>>>(
        src, dst, bucket_cursor, pairs, E, N, total);
    k_build<<<nb, 256, 0, stream>>>(pairs, bucket_ptr, row_ptr, srcs, dinv, N);

    int gemm_blocks = (N + 63) / 64;
    // ---- layer 1: g = bf16(dinv*(x@W1)); act = bf16(relu(dinv*sum(g)+b1)) ----
    k_gemm_mfma<false><<<gemm_blocks, 256, 0, stream>>>(x, Wp1, dinv, gbuf, N);
    k_aggregate<1, 1><<<(N + 3) / 4, 256, 0, stream>>>(row_ptr, srcs, gbuf, dinv, b1, act, N);

    // ---- layer 2: g = bf16(dinv*(act@W2)); out = dinv*sum(g)+b2 ----
    k_gemm_mfma<true><<<gemm_blocks, 256, 0, stream>>>(act, Wp2, dinv, gbuf, N);
    k_aggregate<0, 0><<<(N + 3) / 4, 256, 0, stream>>>(row_ptr, srcs, gbuf, dinv, b2, out, N);
}